// Round 6
// baseline (348.326 us; speedup 1.0000x reference)
//
#include <hip/hip_runtime.h>

#define S_LEN 2048
#define H_DIM 2048
#define NH 32
#define NKV 8
#define HD 64
#define RLEN 1024
#define KVTOT 3072
#define SCALE 0.125f
// SCALE * log2(e): fold into Q during RoPE so QK^T lands in log2 domain
#define QS 0.18033688011112042f
// 8 * log2(e): fixed softmax max in log2 domain
#define FIX8 11.541560327111707f

typedef unsigned short ushort_t;
using short8 = __attribute__((ext_vector_type(8))) short;
using f32x4 = __attribute__((ext_vector_type(4))) float;

__device__ __forceinline__ float b2f(unsigned short u) {
    union { unsigned int i; float f; } v;
    v.i = ((unsigned int)u) << 16;
    return v.f;
}
__device__ __forceinline__ unsigned short f2b(float f) {
    union { float f; unsigned int i; } v;
    v.f = f;
    unsigned int x = v.i;
    return (unsigned short)((x + 0x7fffu + ((x >> 16) & 1u)) >> 16);
}

// async global->LDS, 16B per lane. LDS dest is WAVE-UNIFORM base; HW adds lane*16B.
__device__ __forceinline__ void gload16(const ushort_t* g, ushort_t* l) {
    __builtin_amdgcn_global_load_lds(
        (const __attribute__((address_space(1))) unsigned int*)g,
        (__attribute__((address_space(3))) unsigned int*)l, 16, 0, 0);
}

// ---- dtype detector: flags[b] = 1 if tensor b is f32, 0 if bf16 ----
__global__ void detect9(const void* p0, const void* p1, const void* p2,
                        const void* p3, const void* p4, const void* p5,
                        const void* p6, const void* p7, const void* p8,
                        int* flags)
{
    __shared__ int bad;
    if (threadIdx.x == 0) bad = 0;
    __syncthreads();
    const void* ps[9] = {p0, p1, p2, p3, p4, p5, p6, p7, p8};
    const unsigned int* w = (const unsigned int*)ps[blockIdx.x];
    int cnt = 0;
    for (int i = threadIdx.x; i < 4096; i += blockDim.x) {
        unsigned int lo = w[i] & 0xFFFFu;
        unsigned int e = (lo >> 7) & 0xFFu;
        if (lo != 0u && (e < 90u || e > 140u)) ++cnt;
    }
    atomicAdd(&bad, cnt);
    __syncthreads();
    if (threadIdx.x == 0) flags[blockIdx.x] = (bad > 16) ? 1 : 0;
}

// ---- elementwise cvt dual -> bf16 (8 elems/thread) ----
__global__ void cvt_b(const void* __restrict__ src, ushort_t* __restrict__ dst,
                      int n, const int* __restrict__ F_)
{
    const int F = *F_;
    int i = (blockIdx.x * 256 + threadIdx.x) * 8;
    if (i >= n) return;
    ushort_t o[8];
    if (F) {
        const float* p = (const float*)src + i;
        float4 f0 = ((const float4*)p)[0];
        float4 f1 = ((const float4*)p)[1];
        o[0] = f2b(f0.x); o[1] = f2b(f0.y); o[2] = f2b(f0.z); o[3] = f2b(f0.w);
        o[4] = f2b(f1.x); o[5] = f2b(f1.y); o[6] = f2b(f1.z); o[7] = f2b(f1.w);
        *(uint4*)(dst + i) = *(const uint4*)o;
    } else {
        *(uint4*)(dst + i) = *(const uint4*)((const ushort_t*)src + i);
    }
}

// ---- cvtW: transpose all 4 weights into WqkvT / WoT via blockIdx.z ----
__global__ __launch_bounds__(256) void cvtW(
    const void* __restrict__ Wq, const void* __restrict__ Wk,
    const void* __restrict__ Wv, const void* __restrict__ Wo,
    ushort_t* __restrict__ WqkvT, ushort_t* __restrict__ WoT,
    const int* __restrict__ flags)
{
    const int z = blockIdx.z;
    if ((z == 1 || z == 2) && blockIdx.x >= 8) return;
    const void* src = (z == 0) ? Wq : (z == 1) ? Wk : (z == 2) ? Wv : Wo;
    const int F = flags[5 + z];
    const int C = (z == 1 || z == 2) ? 512 : 2048;
    ushort_t* dst = (z == 3) ? WoT : WqkvT;
    const int rofs = (z == 1) ? 2048 : (z == 2) ? 2560 : 0;

    __shared__ ushort_t S[64 * 72];
    const int r0 = blockIdx.y * 64, c0 = blockIdx.x * 64;
    const int lr = threadIdx.x >> 2, lc = (threadIdx.x & 3) * 16;
    ushort_t t[16];
    if (F) {
        const float* p = (const float*)src + (size_t)(r0 + lr) * C + c0 + lc;
#pragma unroll
        for (int j = 0; j < 16; j += 4) {
            float4 f = *(const float4*)(p + j);
            t[j] = f2b(f.x); t[j + 1] = f2b(f.y); t[j + 2] = f2b(f.z); t[j + 3] = f2b(f.w);
        }
    } else {
        const ushort_t* p = (const ushort_t*)src + (size_t)(r0 + lr) * C + c0 + lc;
        *(uint4*)t = ((const uint4*)p)[0];
        *(uint4*)(t + 8) = ((const uint4*)p)[1];
    }
    *(uint4*)&S[lr * 72 + lc] = *(const uint4*)t;
    *(uint4*)&S[lr * 72 + lc + 8] = *(const uint4*)(t + 8);
    __syncthreads();
    const int wc = threadIdx.x >> 2, wr = (threadIdx.x & 3) * 16;
    ushort_t o[16];
#pragma unroll
    for (int j = 0; j < 16; ++j) o[j] = S[(wr + j) * 72 + wc];
    ushort_t* q = dst + (size_t)(rofs + c0 + wc) * 2048 + r0 + wr;
    *(uint4*)q = *(const uint4*)o;
    *(uint4*)(q + 8) = *(const uint4*)(o + 8);
}

// ---- 64x128-tile MFMA GEMM: gload_lds + counted-vmcnt raw-barrier pipeline ----
__global__ __launch_bounds__(256, 4) void gemm_qkv(
    const ushort_t* __restrict__ A, const ushort_t* __restrict__ Bt,
    ushort_t* __restrict__ C, int N, int K)
{
    __shared__ __align__(16) ushort_t As[2][64 * 32];
    __shared__ __align__(16) ushort_t Bs[2][128 * 32];
    const int tid = threadIdx.x;
    const int wave = tid >> 6, lane = tid & 63;
    const int lq = lane & 15, quad = lane >> 4;
    const int m0 = blockIdx.y * 64, n0 = blockIdx.x * 128;
    const int wm = (wave & 1) * 32, wn = (wave >> 1) * 64;
    const int nk = K >> 5;

    const int srow = wave * 16 + (lane >> 2);
    const int scol = ((lane & 3) ^ ((lane >> 3) & 3)) * 8;   // inverse-swizzled source
    const ushort_t* ga  = A  + (size_t)(m0 + srow) * K + scol;
    const ushort_t* gb0 = Bt + (size_t)(n0 + srow) * K + scol;
    const ushort_t* gb1 = Bt + (size_t)(n0 + 64 + srow) * K + scol;
    ushort_t* lA = &As[0][0] + wave * 16 * 32;   // wave-uniform LDS bases
    ushort_t* lB = &Bs[0][0] + wave * 16 * 32;
    const int rs = (lq >> 1) & 3;                // read-slot swizzle

    f32x4 acc[2][4];
#pragma unroll
    for (int i = 0; i < 2; ++i)
#pragma unroll
        for (int j = 0; j < 4; ++j) acc[i][j] = (f32x4){0.f, 0.f, 0.f, 0.f};

#define STAGE_G(buf, kt) do { \
        gload16(ga  + (size_t)(kt) * 32, lA + (buf) * (64 * 32)); \
        gload16(gb0 + (size_t)(kt) * 32, lB + (buf) * (128 * 32)); \
        gload16(gb1 + (size_t)(kt) * 32, lB + (buf) * (128 * 32) + 64 * 32); \
    } while (0)

    STAGE_G(0, 0);
    int cur = 0;
    for (int kt = 0; kt < nk; ++kt) {
        if (kt + 1 < nk) {
            STAGE_G(cur ^ 1, kt + 1);
            asm volatile("s_waitcnt vmcnt(3)" ::: "memory");
        } else {
            asm volatile("s_waitcnt vmcnt(0)" ::: "memory");
        }
        __builtin_amdgcn_s_barrier();
        __builtin_amdgcn_sched_barrier(0);
        short8 afr[2], bfr[4];
#pragma unroll
        for (int i = 0; i < 2; ++i)
            afr[i] = *(const short8*)&As[cur][(wm + i * 16 + lq) * 32 + (quad ^ rs) * 8];
#pragma unroll
        for (int j = 0; j < 4; ++j)
            bfr[j] = *(const short8*)&Bs[cur][(wn + j * 16 + lq) * 32 + (quad ^ rs) * 8];
#pragma unroll
        for (int i = 0; i < 2; ++i)
#pragma unroll
            for (int j = 0; j < 4; ++j)
                acc[i][j] = __builtin_amdgcn_mfma_f32_16x16x32_bf16(afr[i], bfr[j], acc[i][j], 0, 0, 0);
        __builtin_amdgcn_s_barrier();
        cur ^= 1;
    }

#pragma unroll
    for (int i = 0; i < 2; ++i)
#pragma unroll
        for (int r = 0; r < 4; ++r) {
            ushort_t* cp = C + (size_t)(m0 + wm + i * 16 + quad * 4 + r) * N + n0 + wn + lq;
#pragma unroll
            for (int j = 0; j < 4; ++j) cp[j * 16] = f2b(acc[i][j][r]);
        }
#undef STAGE_G
}

// ---- same pipelined 64x128 structure, dual-dtype output ----
__global__ __launch_bounds__(256, 4) void gemm_fin(
    const ushort_t* __restrict__ A, const ushort_t* __restrict__ Bt,
    void* __restrict__ Cv, int N, int K, const int* __restrict__ oF_)
{
    const int oF = *oF_;
    __shared__ __align__(16) ushort_t As[2][64 * 32];
    __shared__ __align__(16) ushort_t Bs[2][128 * 32];
    const int tid = threadIdx.x;
    const int wave = tid >> 6, lane = tid & 63;
    const int lq = lane & 15, quad = lane >> 4;
    const int m0 = blockIdx.y * 64, n0 = blockIdx.x * 128;
    const int wm = (wave & 1) * 32, wn = (wave >> 1) * 64;
    const int nk = K >> 5;

    const int srow = wave * 16 + (lane >> 2);
    const int scol = ((lane & 3) ^ ((lane >> 3) & 3)) * 8;
    const ushort_t* ga  = A  + (size_t)(m0 + srow) * K + scol;
    const ushort_t* gb0 = Bt + (size_t)(n0 + srow) * K + scol;
    const ushort_t* gb1 = Bt + (size_t)(n0 + 64 + srow) * K + scol;
    ushort_t* lA = &As[0][0] + wave * 16 * 32;
    ushort_t* lB = &Bs[0][0] + wave * 16 * 32;
    const int rs = (lq >> 1) & 3;

    f32x4 acc[2][4];
#pragma unroll
    for (int i = 0; i < 2; ++i)
#pragma unroll
        for (int j = 0; j < 4; ++j) acc[i][j] = (f32x4){0.f, 0.f, 0.f, 0.f};

#define STAGE_G(buf, kt) do { \
        gload16(ga  + (size_t)(kt) * 32, lA + (buf) * (64 * 32)); \
        gload16(gb0 + (size_t)(kt) * 32, lB + (buf) * (128 * 32)); \
        gload16(gb1 + (size_t)(kt) * 32, lB + (buf) * (128 * 32) + 64 * 32); \
    } while (0)

    STAGE_G(0, 0);
    int cur = 0;
    for (int kt = 0; kt < nk; ++kt) {
        if (kt + 1 < nk) {
            STAGE_G(cur ^ 1, kt + 1);
            asm volatile("s_waitcnt vmcnt(3)" ::: "memory");
        } else {
            asm volatile("s_waitcnt vmcnt(0)" ::: "memory");
        }
        __builtin_amdgcn_s_barrier();
        __builtin_amdgcn_sched_barrier(0);
        short8 afr[2], bfr[4];
#pragma unroll
        for (int i = 0; i < 2; ++i)
            afr[i] = *(const short8*)&As[cur][(wm + i * 16 + lq) * 32 + (quad ^ rs) * 8];
#pragma unroll
        for (int j = 0; j < 4; ++j)
            bfr[j] = *(const short8*)&Bs[cur][(wn + j * 16 + lq) * 32 + (quad ^ rs) * 8];
#pragma unroll
        for (int i = 0; i < 2; ++i)
#pragma unroll
            for (int j = 0; j < 4; ++j)
                acc[i][j] = __builtin_amdgcn_mfma_f32_16x16x32_bf16(afr[i], bfr[j], acc[i][j], 0, 0, 0);
        __builtin_amdgcn_s_barrier();
        cur ^= 1;
    }

#pragma unroll
    for (int i = 0; i < 2; ++i)
#pragma unroll
        for (int r = 0; r < 4; ++r) {
            size_t off = (size_t)(m0 + wm + i * 16 + quad * 4 + r) * N + n0 + wn + lq;
            if (oF) {
                float* cp = (float*)Cv + off;
#pragma unroll
                for (int j = 0; j < 4; ++j) cp[j * 16] = acc[i][j][r];
            } else {
                ushort_t* cp = (ushort_t*)Cv + off;
#pragma unroll
                for (int j = 0; j < 4; ++j) cp[j * 16] = f2b(acc[i][j][r]);
            }
        }
#undef STAGE_G
}

// ---- prepKV: z=0 -> V transpose into tiled vtall; z=1 -> K concat + fused RoPE ----
// vtall layout: [kvh][blk(96)][d(64)][32 kv]; ktall: [kvh][kv(3072)][d(64)].
__global__ __launch_bounds__(256) void prepKV(
    const void* __restrict__ rk, const void* __restrict__ rv,
    const ushort_t* __restrict__ qkvp,
    const void* __restrict__ cosv, const void* __restrict__ sinv,
    ushort_t* __restrict__ ktall, ushort_t* __restrict__ vtall,
    const int* __restrict__ flags)
{
    if (blockIdx.z == 0) {
        const int vF = flags[4];
        const int t = blockIdx.x;      // 0..47, <16 retrieval
        const int kvh = blockIdx.y;
        __shared__ ushort_t S[64 * 72];
        const int lr = threadIdx.x >> 2, lc = (threadIdx.x & 3) * 16;
        ushort_t tt[16];
        if (t < 16) {
            size_t base = ((size_t)kvh * RLEN + t * 64 + lr) * HD + lc;
            if (vF) {
                const float* p = (const float*)rv + base;
#pragma unroll
                for (int j = 0; j < 16; j += 4) {
                    float4 f = *(const float4*)(p + j);
                    tt[j] = f2b(f.x); tt[j + 1] = f2b(f.y); tt[j + 2] = f2b(f.z); tt[j + 3] = f2b(f.w);
                }
            } else {
                const ushort_t* p = (const ushort_t*)rv + base;
                *(uint4*)tt = ((const uint4*)p)[0];
                *(uint4*)(tt + 8) = ((const uint4*)p)[1];
            }
        } else {
            const ushort_t* p = qkvp + (size_t)((t - 16) * 64 + lr) * 3072 + 2560 + kvh * HD + lc;
            *(uint4*)tt = ((const uint4*)p)[0];
            *(uint4*)(tt + 8) = ((const uint4*)p)[1];
        }
        *(uint4*)&S[lr * 72 + lc] = *(const uint4*)tt;
        *(uint4*)&S[lr * 72 + lc + 8] = *(const uint4*)(tt + 8);
        __syncthreads();
        const int wc = threadIdx.x >> 2, wr = (threadIdx.x & 3) * 16;
        ushort_t o[16];
#pragma unroll
        for (int j = 0; j < 16; ++j) o[j] = S[(wr + j) * 72 + wc];
        const int blk = t * 2 + (wr >> 5);
        ushort_t* q = vtall + (((size_t)(kvh * 96 + blk) * 64 + wc) * 32) + (wr & 31);
        *(uint4*)q = *(const uint4*)o;
        *(uint4*)(q + 8) = *(const uint4*)(o + 8);
    } else {
        const int kF = flags[3], cF = flags[1], sF = flags[2];
        int flat = (blockIdx.y * 48 + blockIdx.x) * 256 + threadIdx.x;
        const int d0 = (flat & 3) * 8;
        const int p = (flat >> 2) % KVTOT;
        const int kvh = (flat >> 2) / KVTOT;
        ushort_t o0[8], o1[8];
        if (p < RLEN) {
            size_t base = ((size_t)kvh * RLEN + p) * HD;
            if (kF) {
                const float* s = (const float*)rk + base;
#pragma unroll
                for (int j = 0; j < 8; j += 4) {
                    float4 f = *(const float4*)(s + d0 + j);
                    o0[j] = f2b(f.x); o0[j + 1] = f2b(f.y); o0[j + 2] = f2b(f.z); o0[j + 3] = f2b(f.w);
                    float4 g = *(const float4*)(s + d0 + 32 + j);
                    o1[j] = f2b(g.x); o1[j + 1] = f2b(g.y); o1[j + 2] = f2b(g.z); o1[j + 3] = f2b(g.w);
                }
            } else {
                const ushort_t* s = (const ushort_t*)rk + base;
                *(uint4*)o0 = *(const uint4*)(s + d0);
                *(uint4*)o1 = *(const uint4*)(s + d0 + 32);
            }
        } else {
            const int si = p - RLEN;
            const ushort_t* s = qkvp + (size_t)si * 3072 + 2048 + kvh * HD;
            uint4 u0 = *(const uint4*)(s + d0);
            uint4 u1 = *(const uint4*)(s + d0 + 32);
            const ushort_t* a16 = (const ushort_t*)&u0;
            const ushort_t* b16 = (const ushort_t*)&u1;
            int ci = si * HD + d0;
            float c0[8], c1[8], s0[8], s1[8];
            if (cF) {
                const float* cp = (const float*)cosv + ci;
#pragma unroll
                for (int j = 0; j < 8; ++j) { c0[j] = cp[j]; c1[j] = cp[j + 32]; }
            } else {
                const ushort_t* cp = (const ushort_t*)cosv + ci;
#pragma unroll
                for (int j = 0; j < 8; ++j) { c0[j] = b2f(cp[j]); c1[j] = b2f(cp[j + 32]); }
            }
            if (sF) {
                const float* sp = (const float*)sinv + ci;
#pragma unroll
                for (int j = 0; j < 8; ++j) { s0[j] = sp[j]; s1[j] = sp[j + 32]; }
            } else {
                const ushort_t* sp = (const ushort_t*)sinv + ci;
#pragma unroll
                for (int j = 0; j < 8; ++j) { s0[j] = b2f(sp[j]); s1[j] = b2f(sp[j + 32]); }
            }
#pragma unroll
            for (int j = 0; j < 8; ++j) {
                float a = b2f(a16[j]), b = b2f(b16[j]);
                o0[j] = f2b(a * c0[j] - b * s0[j]);
                o1[j] = f2b(b * c1[j] + a * s1[j]);
            }
        }
        ushort_t* q = ktall + ((size_t)kvh * KVTOT + p) * HD;
        *(uint4*)(q + d0) = *(const uint4*)o0;
        *(uint4*)(q + d0 + 32) = *(const uint4*)o1;
    }
}

// ---- Flash attention (R1 version, 69.5us): swapped QK^T + packed P-store ----
__global__ __launch_bounds__(256) void fattn(
    const ushort_t* __restrict__ qkvp, const ushort_t* __restrict__ ktall,
    const ushort_t* __restrict__ vtall, ushort_t* __restrict__ attno,
    const void* __restrict__ cosv, const void* __restrict__ sinv,
    const int* __restrict__ flags)
{
    const int cF = flags[1], sF = flags[2];
    const int h = blockIdx.x;
    // balanced qb map: per-CU work sum constant under round-robin placement
    const int yy = blockIdx.y;
    const int st = yy >> 3, r8 = yy & 7;
    const int qb = (st == 0) ? (31 - r8) : (st == 1) ? (16 + r8)
                 : (st == 2) ? (15 - r8) : r8;
    const int kvh = h >> 2;
    const int tid = threadIdx.x;
    const int wave = tid >> 6;
    const int lane = tid & 63;
    const int lq = lane & 15;
    const int quad = lane >> 4;
    const int rb64 = ((qb < 17 ? qb : 16) - 1) * 64;
    const int qrow = qb * 64 + wave * 16 + lq;   // this lane's q-row (S^T col)

    __shared__ __align__(16) ushort_t Ks[128 * 72];
    __shared__ __align__(16) ushort_t Ps[4 * 16 * 136];
    ushort_t* pw = &Ps[wave * 16 * 136];

    // ---- Q load + fused RoPE, SCALE*log2e folded ----
    short8 qfrag[2];
    {
        const int row_g = qb * 64 + wave * 16 + lq;
        const ushort_t* qrp = qkvp + (size_t)row_g * 3072 + h * HD;
        short8 t0 = *(const short8*)(qrp + quad * 8);
        short8 t1 = *(const short8*)(qrp + 32 + quad * 8);
        const int ci = row_g * HD + quad * 8;
        float c0[8], c1[8], s0[8], s1[8];
        if (cF) {
            const float* cp = (const float*)cosv + ci;
#pragma unroll
            for (int j = 0; j < 8; ++j) { c0[j] = cp[j]; c1[j] = cp[j + 32]; }
        } else {
            const ushort_t* cp = (const ushort_t*)cosv + ci;
#pragma unroll
            for (int j = 0; j < 8; ++j) { c0[j] = b2f(cp[j]); c1[j] = b2f(cp[j + 32]); }
        }
        if (sF) {
            const float* sp = (const float*)sinv + ci;
#pragma unroll
            for (int j = 0; j < 8; ++j) { s0[j] = sp[j]; s1[j] = sp[j + 32]; }
        } else {
            const ushort_t* sp = (const ushort_t*)sinv + ci;
#pragma unroll
            for (int j = 0; j < 8; ++j) { s0[j] = b2f(sp[j]); s1[j] = b2f(sp[j + 32]); }
        }
#pragma unroll
        for (int j = 0; j < 8; ++j) {
            float a = b2f((unsigned short)t0[j]), b = b2f((unsigned short)t1[j]);
            qfrag[0][j] = (short)f2b((a * c0[j] - b * s0[j]) * QS);
            qfrag[1][j] = (short)f2b((b * c1[j] + a * s1[j]) * QS);
        }
    }

    f32x4 oacc[4];
#pragma unroll
    for (int nt = 0; nt < 4; ++nt) oacc[nt] = (f32x4){0.f, 0.f, 0.f, 0.f};
    float lsum = 0.f;

    const int Lq = (qb > 0) ? qb * 64 + 128 : 64;
    const int nch = (Lq + 127) >> 7;
    const ushort_t* kbase = ktall + (size_t)kvh * KVTOT * HD;
    const ushort_t* vbase = vtall + (size_t)kvh * 96 * 2048;

    for (int c = 0; c < nch; ++c) {
        // ---- K staging loads FIRST (so LDS-write waitcnt doesn't drain V loads) ----
        uint4 kreg0, kreg1, kreg2, kreg3;
        const int krow = tid >> 1;
        const int kd0 = (tid & 1) * 32;
        {
            int p = c * 128 + krow;
            uint4 z = {0, 0, 0, 0};
            kreg0 = z; kreg1 = z; kreg2 = z; kreg3 = z;
            if (p < Lq) {
                int pk = (qb > 0) ? ((p < 64) ? rb64 + p : 960 + p) : RLEN + p;
                const uint4* s = (const uint4*)(kbase + (size_t)pk * HD + kd0);
                kreg0 = s[0]; kreg1 = s[1]; kreg2 = s[2]; kreg3 = s[3];
            }
        }
        // ---- V prefetch kc0, kc1 (direct-global frags, consumed in PV) ----
        int vblk[4];
#pragma unroll
        for (int kc = 0; kc < 4; ++kc) {
            int p = c * 128 + kc * 32;
            int pk = (qb > 0) ? ((p < 64) ? rb64 + p : 960 + p) : RLEN + p;
            if (pk > KVTOT - 1) pk = KVTOT - 1;   // clamped keys have P==0 (masked)
            vblk[kc] = pk >> 5;
        }
        short8 vfA[4], vfB[4];
#pragma unroll
        for (int ntd = 0; ntd < 4; ++ntd)
            vfA[ntd] = *(const short8*)(vbase + ((size_t)vblk[0] * 64 + ntd * 16 + lq) * 32 + quad * 8);
#pragma unroll
        for (int ntd = 0; ntd < 4; ++ntd)
            vfB[ntd] = *(const short8*)(vbase + ((size_t)vblk[1] * 64 + ntd * 16 + lq) * 32 + quad * 8);

        // ---- write K to LDS ----
        {
            uint4* dk = (uint4*)&Ks[krow * 72 + kd0];
            dk[0] = kreg0; dk[1] = kreg1; dk[2] = kreg2; dk[3] = kreg3;
        }
        __syncthreads();

        // ---- S^T (log2 domain): mfma(K,Q), exp2, packed b64 P-store ----
        const bool lastc = (c == nch - 1) || (qb == 0);
#pragma unroll
        for (int nt = 0; nt < 8; ++nt) {
            f32x4 a = (f32x4){0.f, 0.f, 0.f, 0.f};
            a = __builtin_amdgcn_mfma_f32_16x16x32_bf16(
                *(const short8*)&Ks[(nt * 16 + lq) * 72 + quad * 8], qfrag[0], a, 0, 0, 0);
            a = __builtin_amdgcn_mfma_f32_16x16x32_bf16(
                *(const short8*)&Ks[(nt * 16 + lq) * 72 + 32 + quad * 8], qfrag[1], a, 0, 0, 0);
            float pex[4];
#pragma unroll
            for (int rr = 0; rr < 4; ++rr) {
                const int p = c * 128 + nt * 16 + quad * 4 + rr;  // local key idx
                float pexp = exp2f(a[rr] - FIX8);
                if (lastc) {
                    bool valid;
                    if (qb > 0) valid = (p < 64) || ((p - 64) >= 1 && (p - 64) <= qrow);
                    else        valid = (p >= 1 && p <= qrow);
                    if (!valid) pexp = 0.f;
                } else if (c == 0) {
                    if (p == 64) pexp = 0.f;   // self position 0 (kv == START)
                }
                lsum += pexp;
                pex[rr] = pexp;
            }
            unsigned int w0, w1;
            asm("v_cvt_pk_bf16_f32 %0, %1, %2" : "=v"(w0) : "v"(pex[0]), "v"(pex[1]));
            asm("v_cvt_pk_bf16_f32 %0, %1, %2" : "=v"(w1) : "v"(pex[2]), "v"(pex[3]));
            *(uint2*)&pw[lq * 136 + nt * 16 + quad * 4] = make_uint2(w0, w1);
        }

        // ---- O += P V : kc0/kc1 from prefetch; kc2/kc3 loaded mid-loop ----
#pragma unroll
        for (int kc = 0; kc < 4; ++kc) {
            short8 pa = *(const short8*)&pw[lq * 136 + kc * 32 + quad * 8];
            short8 vf0, vf1, vf2, vf3;
            if (kc == 0)      { vf0 = vfA[0]; vf1 = vfA[1]; vf2 = vfA[2]; vf3 = vfA[3]; }
            else if (kc == 1) { vf0 = vfB[0]; vf1 = vfB[1]; vf2 = vfB[2]; vf3 = vfB[3]; }
            else {
                const int b = vblk[kc];
                vf0 = *(const short8*)(vbase + ((size_t)b * 64 + 0 * 16 + lq) * 32 + quad * 8);
                vf1 = *(const short8*)(vbase + ((size_t)b * 64 + 1 * 16 + lq) * 32 + quad * 8);
                vf2 = *(const short8*)(vbase + ((size_t)b * 64 + 2 * 16 + lq) * 32 + quad * 8);
                vf3 = *(const short8*)(vbase + ((size_t)b * 64 + 3 * 16 + lq) * 32 + quad * 8);
            }
            oacc[0] = __builtin_amdgcn_mfma_f32_16x16x32_bf16(pa, vf0, oacc[0], 0, 0, 0);
            oacc[1] = __builtin_amdgcn_mfma_f32_16x16x32_bf16(pa, vf1, oacc[1], 0, 0, 0);
            oacc[2] = __builtin_amdgcn_mfma_f32_16x16x32_bf16(pa, vf2, oacc[2], 0, 0, 0);
            oacc[3] = __builtin_amdgcn_mfma_f32_16x16x32_bf16(pa, vf3, oacc[3], 0, 0, 0);
        }
        __syncthreads();
    }

    // ---- epilogue: cross-quad lsum reduce, normalize, write ----
    float tot = lsum;
    tot += __shfl_xor(tot, 16, 64);
    tot += __shfl_xor(tot, 32, 64);
    // lane (quad,lq) now holds total for q-row lq; fetch per output row.
#pragma unroll
    for (int rr = 0; rr < 4; ++rr) {
        const int qg = qb * 64 + wave * 16 + quad * 4 + rr;
        const float tr = __shfl(tot, quad * 4 + rr, 64);
        const float inv = (qg == 0) ? 0.f : 1.f / tr;
        ushort_t* orow = attno + (size_t)qg * 2048 + h * HD;
#pragma unroll
        for (int nt = 0; nt < 4; ++nt)
            orow[nt * 16 + lq] = f2b(oacc[nt][rr] * inv);
    }
}

extern "C" void kernel_launch(void* const* d_in, const int* in_sizes, int n_in,
                              void* d_out, int out_size, void* d_ws, size_t ws_size,
                              hipStream_t stream) {
    const void* hs   = d_in[0];
    const void* cosv = d_in[1];
    const void* sinv = d_in[2];
    const void* rk   = d_in[3];
    const void* rv   = d_in[4];
    const void* Wq   = d_in[5];
    const void* Wk   = d_in[6];
    const void* Wv   = d_in[7];
    const void* Wo   = d_in[8];

    char* ws = (char*)d_ws;
    int*      flags  = (int*)ws;                          // @0
    ushort_t* hsb    = (ushort_t*)(ws + (1u  << 20));     // 1..9 MB (dead after gemm_qkv)
    ushort_t* ktall  = hsb;                               // aliases dead hsb
    ushort_t* vtall  = (ushort_t*)(ws + (1u << 20) + (13u << 18));
    ushort_t* WqkvT  = (ushort_t*)(ws + (9u  << 20));     // 9..21 MB [3072][2048]
    ushort_t* attno  = WqkvT;                             // after WqkvT dead
    ushort_t* WoT    = (ushort_t*)(ws + (21u << 20));     // 21..29 MB
    ushort_t* qkvp   = (ushort_t*)(ws + (29u << 20));     // 29..41 MB [2048][3072]

    detect9<<<9, 256, 0, stream>>>(hs, cosv, sinv, rk, rv, Wq, Wk, Wv, Wo, flags);

    cvt_b<<<(H_DIM * S_LEN / 8 + 255) / 256, 256, 0, stream>>>(hs, hsb, H_DIM * S_LEN, flags + 0);
    cvtW<<<dim3(32, 32, 4), 256, 0, stream>>>(Wq, Wk, Wv, Wo, WqkvT, WoT, flags);

    // MEASUREMENT PROBE (R6): each GEMM launched TWICE (idempotent -- hsb is
    // intact until prepKV; attno intact after fattn). Delta vs R5's 267.8us
    // = T_qkv + T_fin. Output bit-identical.
    gemm_qkv<<<dim3(3072 / 128, 2048 / 64), 256, 0, stream>>>(hsb, WqkvT, qkvp, 3072, 2048);
    gemm_qkv<<<dim3(3072 / 128, 2048 / 64), 256, 0, stream>>>(hsb, WqkvT, qkvp, 3072, 2048);

    prepKV<<<dim3(48, 8, 2), 256, 0, stream>>>(rk, rv, qkvp, cosv, sinv, ktall, vtall, flags);

    fattn<<<dim3(NH, 32), 256, 0, stream>>>(qkvp, ktall, vtall, attno, cosv, sinv, flags);

    gemm_fin<<<dim3(2048 / 128, 2048 / 64), 256, 0, stream>>>(attno, WoT, d_out, 2048, 2048, flags + 0);
    gemm_fin<<<dim3(2048 / 128, 2048 / 64), 256, 0, stream>>>(attno, WoT, d_out, 2048, 2048, flags + 0);
}

// Round 7
// 256.524 us; speedup vs baseline: 1.3579x; 1.3579x over previous
//
#include <hip/hip_runtime.h>

#define S_LEN 2048
#define H_DIM 2048
#define NH 32
#define NKV 8
#define HD 64
#define RLEN 1024
#define KVTOT 3072
#define SCALE 0.125f
// SCALE * log2(e): fold into Q during RoPE so QK^T lands in log2 domain
#define QS 0.18033688011112042f
// 8 * log2(e): fixed softmax max in log2 domain
#define FIX8 11.541560327111707f

typedef unsigned short ushort_t;
using short8 = __attribute__((ext_vector_type(8))) short;
using f32x4 = __attribute__((ext_vector_type(4))) float;

__device__ __forceinline__ float b2f(unsigned short u) {
    union { unsigned int i; float f; } v;
    v.i = ((unsigned int)u) << 16;
    return v.f;
}
__device__ __forceinline__ unsigned short f2b(float f) {
    union { float f; unsigned int i; } v;
    v.f = f;
    unsigned int x = v.i;
    return (unsigned short)((x + 0x7fffu + ((x >> 16) & 1u)) >> 16);
}

// async global->LDS, 16B per lane. LDS dest is WAVE-UNIFORM base; HW adds lane*16B.
__device__ __forceinline__ void gload16(const ushort_t* g, ushort_t* l) {
    __builtin_amdgcn_global_load_lds(
        (const __attribute__((address_space(1))) unsigned int*)g,
        (__attribute__((address_space(3))) unsigned int*)l, 16, 0, 0);
}

// ---- wave-uniform dtype self-detection (replaces detect9 kernel) ----
// Samples the first 1KB (256 words). Same exponent-window rule as the old
// detect9: f32 random low-16 bits -> ~80% flagged; bf16 -> ~0%. All waves of
// all blocks compute the identical answer (same data, same rule) -> the
// removed cross-kernel flags dependency is preserved exactly.
__device__ __forceinline__ int is_f32(const void* p) {
    const unsigned int* w = (const unsigned int*)p;
    const int lane = threadIdx.x & 63;
    int cnt = 0;
#pragma unroll
    for (int j = 0; j < 4; ++j) {
        unsigned int lo = w[lane + j * 64] & 0xFFFFu;
        unsigned int e = (lo >> 7) & 0xFFu;
        cnt += (lo != 0u && (e < 90u || e > 140u)) ? 1 : 0;
    }
    unsigned long long b = __ballot(cnt >= 2);
    return __popcll(b) > 16;
}

// ---- prep_all: fused cvt_b (hs->bf16) + cvtW (4 weight transposes) ----
// id < 2048: hs conversion block; id >= 2048: weight transpose tiles.
// One dispatch instead of detect9 + cvt_b + cvtW (3 serialized launches).
__global__ __launch_bounds__(256) void prep_all(
    const void* __restrict__ hs, ushort_t* __restrict__ hsb,
    const void* __restrict__ Wq, const void* __restrict__ Wk,
    const void* __restrict__ Wv, const void* __restrict__ Wo,
    ushort_t* __restrict__ WqkvT, ushort_t* __restrict__ WoT)
{
    __shared__ ushort_t S[64 * 72];
    const int id = blockIdx.x;
    if (id < 2048) {
        const int F = is_f32(hs);
        int i = (id * 256 + threadIdx.x) * 8;
        ushort_t o[8];
        if (F) {
            const float* p = (const float*)hs + i;
            float4 f0 = ((const float4*)p)[0];
            float4 f1 = ((const float4*)p)[1];
            o[0] = f2b(f0.x); o[1] = f2b(f0.y); o[2] = f2b(f0.z); o[3] = f2b(f0.w);
            o[4] = f2b(f1.x); o[5] = f2b(f1.y); o[6] = f2b(f1.z); o[7] = f2b(f1.w);
            *(uint4*)(hsb + i) = *(const uint4*)o;
        } else {
            *(uint4*)(hsb + i) = *(const uint4*)((const ushort_t*)hs + i);
        }
        return;
    }
    int z, t;
    if (id < 3072)      { z = 0; t = id - 2048; }
    else if (id < 3328) { z = 1; t = id - 3072; }
    else if (id < 3584) { z = 2; t = id - 3328; }
    else                { z = 3; t = id - 3584; }
    const void* src = (z == 0) ? Wq : (z == 1) ? Wk : (z == 2) ? Wv : Wo;
    const int F = is_f32(src);
    const int C = (z == 1 || z == 2) ? 512 : 2048;
    const int nx = (z == 1 || z == 2) ? 8 : 32;
    const int x = t % nx, y = t / nx;
    ushort_t* dst = (z == 3) ? WoT : WqkvT;
    const int rofs = (z == 1) ? 2048 : (z == 2) ? 2560 : 0;

    const int r0 = y * 64, c0 = x * 64;
    const int lr = threadIdx.x >> 2, lc = (threadIdx.x & 3) * 16;
    ushort_t tt[16];
    if (F) {
        const float* p = (const float*)src + (size_t)(r0 + lr) * C + c0 + lc;
#pragma unroll
        for (int j = 0; j < 16; j += 4) {
            float4 f = *(const float4*)(p + j);
            tt[j] = f2b(f.x); tt[j + 1] = f2b(f.y); tt[j + 2] = f2b(f.z); tt[j + 3] = f2b(f.w);
        }
    } else {
        const ushort_t* p = (const ushort_t*)src + (size_t)(r0 + lr) * C + c0 + lc;
        *(uint4*)tt = ((const uint4*)p)[0];
        *(uint4*)(tt + 8) = ((const uint4*)p)[1];
    }
    *(uint4*)&S[lr * 72 + lc] = *(const uint4*)tt;
    *(uint4*)&S[lr * 72 + lc + 8] = *(const uint4*)(tt + 8);
    __syncthreads();
    const int wc = threadIdx.x >> 2, wr = (threadIdx.x & 3) * 16;
    ushort_t o[16];
#pragma unroll
    for (int j = 0; j < 16; ++j) o[j] = S[(wr + j) * 72 + wc];
    ushort_t* q = dst + (size_t)(rofs + c0 + wc) * 2048 + r0 + wr;
    *(uint4*)q = *(const uint4*)o;
    *(uint4*)(q + 8) = *(const uint4*)(o + 8);
}

// ---- 64x128-tile MFMA GEMM: gload_lds + counted-vmcnt raw-barrier pipeline ----
__global__ __launch_bounds__(256, 4) void gemm_qkv(
    const ushort_t* __restrict__ A, const ushort_t* __restrict__ Bt,
    ushort_t* __restrict__ C, int N, int K)
{
    __shared__ __align__(16) ushort_t As[2][64 * 32];
    __shared__ __align__(16) ushort_t Bs[2][128 * 32];
    const int tid = threadIdx.x;
    const int wave = tid >> 6, lane = tid & 63;
    const int lq = lane & 15, quad = lane >> 4;
    const int m0 = blockIdx.y * 64, n0 = blockIdx.x * 128;
    const int wm = (wave & 1) * 32, wn = (wave >> 1) * 64;
    const int nk = K >> 5;

    const int srow = wave * 16 + (lane >> 2);
    const int scol = ((lane & 3) ^ ((lane >> 3) & 3)) * 8;   // inverse-swizzled source
    const ushort_t* ga  = A  + (size_t)(m0 + srow) * K + scol;
    const ushort_t* gb0 = Bt + (size_t)(n0 + srow) * K + scol;
    const ushort_t* gb1 = Bt + (size_t)(n0 + 64 + srow) * K + scol;
    ushort_t* lA = &As[0][0] + wave * 16 * 32;   // wave-uniform LDS bases
    ushort_t* lB = &Bs[0][0] + wave * 16 * 32;
    const int rs = (lq >> 1) & 3;                // read-slot swizzle

    f32x4 acc[2][4];
#pragma unroll
    for (int i = 0; i < 2; ++i)
#pragma unroll
        for (int j = 0; j < 4; ++j) acc[i][j] = (f32x4){0.f, 0.f, 0.f, 0.f};

#define STAGE_G(buf, kt) do { \
        gload16(ga  + (size_t)(kt) * 32, lA + (buf) * (64 * 32)); \
        gload16(gb0 + (size_t)(kt) * 32, lB + (buf) * (128 * 32)); \
        gload16(gb1 + (size_t)(kt) * 32, lB + (buf) * (128 * 32) + 64 * 32); \
    } while (0)

    STAGE_G(0, 0);
    int cur = 0;
    for (int kt = 0; kt < nk; ++kt) {
        if (kt + 1 < nk) {
            STAGE_G(cur ^ 1, kt + 1);
            asm volatile("s_waitcnt vmcnt(3)" ::: "memory");
        } else {
            asm volatile("s_waitcnt vmcnt(0)" ::: "memory");
        }
        __builtin_amdgcn_s_barrier();
        __builtin_amdgcn_sched_barrier(0);
        short8 afr[2], bfr[4];
#pragma unroll
        for (int i = 0; i < 2; ++i)
            afr[i] = *(const short8*)&As[cur][(wm + i * 16 + lq) * 32 + (quad ^ rs) * 8];
#pragma unroll
        for (int j = 0; j < 4; ++j)
            bfr[j] = *(const short8*)&Bs[cur][(wn + j * 16 + lq) * 32 + (quad ^ rs) * 8];
#pragma unroll
        for (int i = 0; i < 2; ++i)
#pragma unroll
            for (int j = 0; j < 4; ++j)
                acc[i][j] = __builtin_amdgcn_mfma_f32_16x16x32_bf16(afr[i], bfr[j], acc[i][j], 0, 0, 0);
        __builtin_amdgcn_s_barrier();
        cur ^= 1;
    }

#pragma unroll
    for (int i = 0; i < 2; ++i)
#pragma unroll
        for (int r = 0; r < 4; ++r) {
            ushort_t* cp = C + (size_t)(m0 + wm + i * 16 + quad * 4 + r) * N + n0 + wn + lq;
#pragma unroll
            for (int j = 0; j < 4; ++j) cp[j * 16] = f2b(acc[i][j][r]);
        }
#undef STAGE_G
}

// ---- same pipelined 64x128 structure, dual-dtype output (self-detects via hs) ----
__global__ __launch_bounds__(256, 4) void gemm_fin(
    const ushort_t* __restrict__ A, const ushort_t* __restrict__ Bt,
    void* __restrict__ Cv, int N, int K, const void* __restrict__ hs)
{
    const int oF = is_f32(hs);
    __shared__ __align__(16) ushort_t As[2][64 * 32];
    __shared__ __align__(16) ushort_t Bs[2][128 * 32];
    const int tid = threadIdx.x;
    const int wave = tid >> 6, lane = tid & 63;
    const int lq = lane & 15, quad = lane >> 4;
    const int m0 = blockIdx.y * 64, n0 = blockIdx.x * 128;
    const int wm = (wave & 1) * 32, wn = (wave >> 1) * 64;
    const int nk = K >> 5;

    const int srow = wave * 16 + (lane >> 2);
    const int scol = ((lane & 3) ^ ((lane >> 3) & 3)) * 8;
    const ushort_t* ga  = A  + (size_t)(m0 + srow) * K + scol;
    const ushort_t* gb0 = Bt + (size_t)(n0 + srow) * K + scol;
    const ushort_t* gb1 = Bt + (size_t)(n0 + 64 + srow) * K + scol;
    ushort_t* lA = &As[0][0] + wave * 16 * 32;
    ushort_t* lB = &Bs[0][0] + wave * 16 * 32;
    const int rs = (lq >> 1) & 3;

    f32x4 acc[2][4];
#pragma unroll
    for (int i = 0; i < 2; ++i)
#pragma unroll
        for (int j = 0; j < 4; ++j) acc[i][j] = (f32x4){0.f, 0.f, 0.f, 0.f};

#define STAGE_G(buf, kt) do { \
        gload16(ga  + (size_t)(kt) * 32, lA + (buf) * (64 * 32)); \
        gload16(gb0 + (size_t)(kt) * 32, lB + (buf) * (128 * 32)); \
        gload16(gb1 + (size_t)(kt) * 32, lB + (buf) * (128 * 32) + 64 * 32); \
    } while (0)

    STAGE_G(0, 0);
    int cur = 0;
    for (int kt = 0; kt < nk; ++kt) {
        if (kt + 1 < nk) {
            STAGE_G(cur ^ 1, kt + 1);
            asm volatile("s_waitcnt vmcnt(3)" ::: "memory");
        } else {
            asm volatile("s_waitcnt vmcnt(0)" ::: "memory");
        }
        __builtin_amdgcn_s_barrier();
        __builtin_amdgcn_sched_barrier(0);
        short8 afr[2], bfr[4];
#pragma unroll
        for (int i = 0; i < 2; ++i)
            afr[i] = *(const short8*)&As[cur][(wm + i * 16 + lq) * 32 + (quad ^ rs) * 8];
#pragma unroll
        for (int j = 0; j < 4; ++j)
            bfr[j] = *(const short8*)&Bs[cur][(wn + j * 16 + lq) * 32 + (quad ^ rs) * 8];
#pragma unroll
        for (int i = 0; i < 2; ++i)
#pragma unroll
            for (int j = 0; j < 4; ++j)
                acc[i][j] = __builtin_amdgcn_mfma_f32_16x16x32_bf16(afr[i], bfr[j], acc[i][j], 0, 0, 0);
        __builtin_amdgcn_s_barrier();
        cur ^= 1;
    }

#pragma unroll
    for (int i = 0; i < 2; ++i)
#pragma unroll
        for (int r = 0; r < 4; ++r) {
            size_t off = (size_t)(m0 + wm + i * 16 + quad * 4 + r) * N + n0 + wn + lq;
            if (oF) {
                float* cp = (float*)Cv + off;
#pragma unroll
                for (int j = 0; j < 4; ++j) cp[j * 16] = acc[i][j][r];
            } else {
                ushort_t* cp = (ushort_t*)Cv + off;
#pragma unroll
                for (int j = 0; j < 4; ++j) cp[j * 16] = f2b(acc[i][j][r]);
            }
        }
#undef STAGE_G
}

// ---- prepKV: z=0 -> V transpose into tiled vtall; z=1 -> K concat + fused RoPE ----
// vtall layout: [kvh][blk(96)][d(64)][32 kv]; ktall: [kvh][kv(3072)][d(64)].
__global__ __launch_bounds__(256) void prepKV(
    const void* __restrict__ rk, const void* __restrict__ rv,
    const ushort_t* __restrict__ qkvp,
    const void* __restrict__ cosv, const void* __restrict__ sinv,
    ushort_t* __restrict__ ktall, ushort_t* __restrict__ vtall)
{
    if (blockIdx.z == 0) {
        const int vF = is_f32(rv);
        const int t = blockIdx.x;      // 0..47, <16 retrieval
        const int kvh = blockIdx.y;
        __shared__ ushort_t S[64 * 72];
        const int lr = threadIdx.x >> 2, lc = (threadIdx.x & 3) * 16;
        ushort_t tt[16];
        if (t < 16) {
            size_t base = ((size_t)kvh * RLEN + t * 64 + lr) * HD + lc;
            if (vF) {
                const float* p = (const float*)rv + base;
#pragma unroll
                for (int j = 0; j < 16; j += 4) {
                    float4 f = *(const float4*)(p + j);
                    tt[j] = f2b(f.x); tt[j + 1] = f2b(f.y); tt[j + 2] = f2b(f.z); tt[j + 3] = f2b(f.w);
                }
            } else {
                const ushort_t* p = (const ushort_t*)rv + base;
                *(uint4*)tt = ((const uint4*)p)[0];
                *(uint4*)(tt + 8) = ((const uint4*)p)[1];
            }
        } else {
            const ushort_t* p = qkvp + (size_t)((t - 16) * 64 + lr) * 3072 + 2560 + kvh * HD + lc;
            *(uint4*)tt = ((const uint4*)p)[0];
            *(uint4*)(tt + 8) = ((const uint4*)p)[1];
        }
        *(uint4*)&S[lr * 72 + lc] = *(const uint4*)tt;
        *(uint4*)&S[lr * 72 + lc + 8] = *(const uint4*)(tt + 8);
        __syncthreads();
        const int wc = threadIdx.x >> 2, wr = (threadIdx.x & 3) * 16;
        ushort_t o[16];
#pragma unroll
        for (int j = 0; j < 16; ++j) o[j] = S[(wr + j) * 72 + wc];
        const int blk = t * 2 + (wr >> 5);
        ushort_t* q = vtall + (((size_t)(kvh * 96 + blk) * 64 + wc) * 32) + (wr & 31);
        *(uint4*)q = *(const uint4*)o;
        *(uint4*)(q + 8) = *(const uint4*)(o + 8);
    } else {
        const int kF = is_f32(rk), cF = is_f32(cosv), sF = is_f32(sinv);
        int flat = (blockIdx.y * 48 + blockIdx.x) * 256 + threadIdx.x;
        const int d0 = (flat & 3) * 8;
        const int p = (flat >> 2) % KVTOT;
        const int kvh = (flat >> 2) / KVTOT;
        ushort_t o0[8], o1[8];
        if (p < RLEN) {
            size_t base = ((size_t)kvh * RLEN + p) * HD;
            if (kF) {
                const float* s = (const float*)rk + base;
#pragma unroll
                for (int j = 0; j < 8; j += 4) {
                    float4 f = *(const float4*)(s + d0 + j);
                    o0[j] = f2b(f.x); o0[j + 1] = f2b(f.y); o0[j + 2] = f2b(f.z); o0[j + 3] = f2b(f.w);
                    float4 g = *(const float4*)(s + d0 + 32 + j);
                    o1[j] = f2b(g.x); o1[j + 1] = f2b(g.y); o1[j + 2] = f2b(g.z); o1[j + 3] = f2b(g.w);
                }
            } else {
                const ushort_t* s = (const ushort_t*)rk + base;
                *(uint4*)o0 = *(const uint4*)(s + d0);
                *(uint4*)o1 = *(const uint4*)(s + d0 + 32);
            }
        } else {
            const int si = p - RLEN;
            const ushort_t* s = qkvp + (size_t)si * 3072 + 2048 + kvh * HD;
            uint4 u0 = *(const uint4*)(s + d0);
            uint4 u1 = *(const uint4*)(s + d0 + 32);
            const ushort_t* a16 = (const ushort_t*)&u0;
            const ushort_t* b16 = (const ushort_t*)&u1;
            int ci = si * HD + d0;
            float c0[8], c1[8], s0[8], s1[8];
            if (cF) {
                const float* cp = (const float*)cosv + ci;
#pragma unroll
                for (int j = 0; j < 8; ++j) { c0[j] = cp[j]; c1[j] = cp[j + 32]; }
            } else {
                const ushort_t* cp = (const ushort_t*)cosv + ci;
#pragma unroll
                for (int j = 0; j < 8; ++j) { c0[j] = b2f(cp[j]); c1[j] = b2f(cp[j + 32]); }
            }
            if (sF) {
                const float* sp = (const float*)sinv + ci;
#pragma unroll
                for (int j = 0; j < 8; ++j) { s0[j] = sp[j]; s1[j] = sp[j + 32]; }
            } else {
                const ushort_t* sp = (const ushort_t*)sinv + ci;
#pragma unroll
                for (int j = 0; j < 8; ++j) { s0[j] = b2f(sp[j]); s1[j] = b2f(sp[j + 32]); }
            }
#pragma unroll
            for (int j = 0; j < 8; ++j) {
                float a = b2f(a16[j]), b = b2f(b16[j]);
                o0[j] = f2b(a * c0[j] - b * s0[j]);
                o1[j] = f2b(b * c1[j] + a * s1[j]);
            }
        }
        ushort_t* q = ktall + ((size_t)kvh * KVTOT + p) * HD;
        *(uint4*)(q + d0) = *(const uint4*)o0;
        *(uint4*)(q + d0 + 32) = *(const uint4*)o1;
    }
}

// ---- Flash attention (R1 version, 69.5us): swapped QK^T + packed P-store ----
__global__ __launch_bounds__(256) void fattn(
    const ushort_t* __restrict__ qkvp, const ushort_t* __restrict__ ktall,
    const ushort_t* __restrict__ vtall, ushort_t* __restrict__ attno,
    const void* __restrict__ cosv, const void* __restrict__ sinv)
{
    const int cF = is_f32(cosv), sF = is_f32(sinv);
    const int h = blockIdx.x;
    // balanced qb map: per-CU work sum constant under round-robin placement
    const int yy = blockIdx.y;
    const int st = yy >> 3, r8 = yy & 7;
    const int qb = (st == 0) ? (31 - r8) : (st == 1) ? (16 + r8)
                 : (st == 2) ? (15 - r8) : r8;
    const int kvh = h >> 2;
    const int tid = threadIdx.x;
    const int wave = tid >> 6;
    const int lane = tid & 63;
    const int lq = lane & 15;
    const int quad = lane >> 4;
    const int rb64 = ((qb < 17 ? qb : 16) - 1) * 64;
    const int qrow = qb * 64 + wave * 16 + lq;   // this lane's q-row (S^T col)

    __shared__ __align__(16) ushort_t Ks[128 * 72];
    __shared__ __align__(16) ushort_t Ps[4 * 16 * 136];
    ushort_t* pw = &Ps[wave * 16 * 136];

    // ---- Q load + fused RoPE, SCALE*log2e folded ----
    short8 qfrag[2];
    {
        const int row_g = qb * 64 + wave * 16 + lq;
        const ushort_t* qrp = qkvp + (size_t)row_g * 3072 + h * HD;
        short8 t0 = *(const short8*)(qrp + quad * 8);
        short8 t1 = *(const short8*)(qrp + 32 + quad * 8);
        const int ci = row_g * HD + quad * 8;
        float c0[8], c1[8], s0[8], s1[8];
        if (cF) {
            const float* cp = (const float*)cosv + ci;
#pragma unroll
            for (int j = 0; j < 8; ++j) { c0[j] = cp[j]; c1[j] = cp[j + 32]; }
        } else {
            const ushort_t* cp = (const ushort_t*)cosv + ci;
#pragma unroll
            for (int j = 0; j < 8; ++j) { c0[j] = b2f(cp[j]); c1[j] = b2f(cp[j + 32]); }
        }
        if (sF) {
            const float* sp = (const float*)sinv + ci;
#pragma unroll
            for (int j = 0; j < 8; ++j) { s0[j] = sp[j]; s1[j] = sp[j + 32]; }
        } else {
            const ushort_t* sp = (const ushort_t*)sinv + ci;
#pragma unroll
            for (int j = 0; j < 8; ++j) { s0[j] = b2f(sp[j]); s1[j] = b2f(sp[j + 32]); }
        }
#pragma unroll
        for (int j = 0; j < 8; ++j) {
            float a = b2f((unsigned short)t0[j]), b = b2f((unsigned short)t1[j]);
            qfrag[0][j] = (short)f2b((a * c0[j] - b * s0[j]) * QS);
            qfrag[1][j] = (short)f2b((b * c1[j] + a * s1[j]) * QS);
        }
    }

    f32x4 oacc[4];
#pragma unroll
    for (int nt = 0; nt < 4; ++nt) oacc[nt] = (f32x4){0.f, 0.f, 0.f, 0.f};
    float lsum = 0.f;

    const int Lq = (qb > 0) ? qb * 64 + 128 : 64;
    const int nch = (Lq + 127) >> 7;
    const ushort_t* kbase = ktall + (size_t)kvh * KVTOT * HD;
    const ushort_t* vbase = vtall + (size_t)kvh * 96 * 2048;

    for (int c = 0; c < nch; ++c) {
        // ---- K staging loads FIRST (so LDS-write waitcnt doesn't drain V loads) ----
        uint4 kreg0, kreg1, kreg2, kreg3;
        const int krow = tid >> 1;
        const int kd0 = (tid & 1) * 32;
        {
            int p = c * 128 + krow;
            uint4 z = {0, 0, 0, 0};
            kreg0 = z; kreg1 = z; kreg2 = z; kreg3 = z;
            if (p < Lq) {
                int pk = (qb > 0) ? ((p < 64) ? rb64 + p : 960 + p) : RLEN + p;
                const uint4* s = (const uint4*)(kbase + (size_t)pk * HD + kd0);
                kreg0 = s[0]; kreg1 = s[1]; kreg2 = s[2]; kreg3 = s[3];
            }
        }
        // ---- V prefetch kc0, kc1 (direct-global frags, consumed in PV) ----
        int vblk[4];
#pragma unroll
        for (int kc = 0; kc < 4; ++kc) {
            int p = c * 128 + kc * 32;
            int pk = (qb > 0) ? ((p < 64) ? rb64 + p : 960 + p) : RLEN + p;
            if (pk > KVTOT - 1) pk = KVTOT - 1;   // clamped keys have P==0 (masked)
            vblk[kc] = pk >> 5;
        }
        short8 vfA[4], vfB[4];
#pragma unroll
        for (int ntd = 0; ntd < 4; ++ntd)
            vfA[ntd] = *(const short8*)(vbase + ((size_t)vblk[0] * 64 + ntd * 16 + lq) * 32 + quad * 8);
#pragma unroll
        for (int ntd = 0; ntd < 4; ++ntd)
            vfB[ntd] = *(const short8*)(vbase + ((size_t)vblk[1] * 64 + ntd * 16 + lq) * 32 + quad * 8);

        // ---- write K to LDS ----
        {
            uint4* dk = (uint4*)&Ks[krow * 72 + kd0];
            dk[0] = kreg0; dk[1] = kreg1; dk[2] = kreg2; dk[3] = kreg3;
        }
        __syncthreads();

        // ---- S^T (log2 domain): mfma(K,Q), exp2, packed b64 P-store ----
        const bool lastc = (c == nch - 1) || (qb == 0);
#pragma unroll
        for (int nt = 0; nt < 8; ++nt) {
            f32x4 a = (f32x4){0.f, 0.f, 0.f, 0.f};
            a = __builtin_amdgcn_mfma_f32_16x16x32_bf16(
                *(const short8*)&Ks[(nt * 16 + lq) * 72 + quad * 8], qfrag[0], a, 0, 0, 0);
            a = __builtin_amdgcn_mfma_f32_16x16x32_bf16(
                *(const short8*)&Ks[(nt * 16 + lq) * 72 + 32 + quad * 8], qfrag[1], a, 0, 0, 0);
            float pex[4];
#pragma unroll
            for (int rr = 0; rr < 4; ++rr) {
                const int p = c * 128 + nt * 16 + quad * 4 + rr;  // local key idx
                float pexp = exp2f(a[rr] - FIX8);
                if (lastc) {
                    bool valid;
                    if (qb > 0) valid = (p < 64) || ((p - 64) >= 1 && (p - 64) <= qrow);
                    else        valid = (p >= 1 && p <= qrow);
                    if (!valid) pexp = 0.f;
                } else if (c == 0) {
                    if (p == 64) pexp = 0.f;   // self position 0 (kv == START)
                }
                lsum += pexp;
                pex[rr] = pexp;
            }
            unsigned int w0, w1;
            asm("v_cvt_pk_bf16_f32 %0, %1, %2" : "=v"(w0) : "v"(pex[0]), "v"(pex[1]));
            asm("v_cvt_pk_bf16_f32 %0, %1, %2" : "=v"(w1) : "v"(pex[2]), "v"(pex[3]));
            *(uint2*)&pw[lq * 136 + nt * 16 + quad * 4] = make_uint2(w0, w1);
        }

        // ---- O += P V : kc0/kc1 from prefetch; kc2/kc3 loaded mid-loop ----
#pragma unroll
        for (int kc = 0; kc < 4; ++kc) {
            short8 pa = *(const short8*)&pw[lq * 136 + kc * 32 + quad * 8];
            short8 vf0, vf1, vf2, vf3;
            if (kc == 0)      { vf0 = vfA[0]; vf1 = vfA[1]; vf2 = vfA[2]; vf3 = vfA[3]; }
            else if (kc == 1) { vf0 = vfB[0]; vf1 = vfB[1]; vf2 = vfB[2]; vf3 = vfB[3]; }
            else {
                const int b = vblk[kc];
                vf0 = *(const short8*)(vbase + ((size_t)b * 64 + 0 * 16 + lq) * 32 + quad * 8);
                vf1 = *(const short8*)(vbase + ((size_t)b * 64 + 1 * 16 + lq) * 32 + quad * 8);
                vf2 = *(const short8*)(vbase + ((size_t)b * 64 + 2 * 16 + lq) * 32 + quad * 8);
                vf3 = *(const short8*)(vbase + ((size_t)b * 64 + 3 * 16 + lq) * 32 + quad * 8);
            }
            oacc[0] = __builtin_amdgcn_mfma_f32_16x16x32_bf16(pa, vf0, oacc[0], 0, 0, 0);
            oacc[1] = __builtin_amdgcn_mfma_f32_16x16x32_bf16(pa, vf1, oacc[1], 0, 0, 0);
            oacc[2] = __builtin_amdgcn_mfma_f32_16x16x32_bf16(pa, vf2, oacc[2], 0, 0, 0);
            oacc[3] = __builtin_amdgcn_mfma_f32_16x16x32_bf16(pa, vf3, oacc[3], 0, 0, 0);
        }
        __syncthreads();
    }

    // ---- epilogue: cross-quad lsum reduce, normalize, write ----
    float tot = lsum;
    tot += __shfl_xor(tot, 16, 64);
    tot += __shfl_xor(tot, 32, 64);
    // lane (quad,lq) now holds total for q-row lq; fetch per output row.
#pragma unroll
    for (int rr = 0; rr < 4; ++rr) {
        const int qg = qb * 64 + wave * 16 + quad * 4 + rr;
        const float tr = __shfl(tot, quad * 4 + rr, 64);
        const float inv = (qg == 0) ? 0.f : 1.f / tr;
        ushort_t* orow = attno + (size_t)qg * 2048 + h * HD;
#pragma unroll
        for (int nt = 0; nt < 4; ++nt)
            orow[nt * 16 + lq] = f2b(oacc[nt][rr] * inv);
    }
}

extern "C" void kernel_launch(void* const* d_in, const int* in_sizes, int n_in,
                              void* d_out, int out_size, void* d_ws, size_t ws_size,
                              hipStream_t stream) {
    const void* hs   = d_in[0];
    const void* cosv = d_in[1];
    const void* sinv = d_in[2];
    const void* rk   = d_in[3];
    const void* rv   = d_in[4];
    const void* Wq   = d_in[5];
    const void* Wk   = d_in[6];
    const void* Wv   = d_in[7];
    const void* Wo   = d_in[8];

    char* ws = (char*)d_ws;
    ushort_t* hsb    = (ushort_t*)(ws + (1u  << 20));     // 1..9 MB (dead after gemm_qkv)
    ushort_t* ktall  = hsb;                               // aliases dead hsb
    ushort_t* vtall  = (ushort_t*)(ws + (1u << 20) + (13u << 18));
    ushort_t* WqkvT  = (ushort_t*)(ws + (9u  << 20));     // 9..21 MB [3072][2048]
    ushort_t* attno  = WqkvT;                             // after WqkvT dead
    ushort_t* WoT    = (ushort_t*)(ws + (21u << 20));     // 21..29 MB
    ushort_t* qkvp   = (ushort_t*)(ws + (29u << 20));     // 29..41 MB [2048][3072]

    // 5-dispatch chain (was 7): detect9 eliminated via in-kernel self-detect;
    // cvt_b + cvtW fused into prep_all.
    prep_all<<<4608, 256, 0, stream>>>(hs, hsb, Wq, Wk, Wv, Wo, WqkvT, WoT);

    gemm_qkv<<<dim3(3072 / 128, 2048 / 64), 256, 0, stream>>>(hsb, WqkvT, qkvp, 3072, 2048);

    prepKV<<<dim3(48, 8, 2), 256, 0, stream>>>(rk, rv, qkvp, cosv, sinv, ktall, vtall);

    fattn<<<dim3(NH, 32), 256, 0, stream>>>(qkvp, ktall, vtall, attno, cosv, sinv);

    gemm_fin<<<dim3(2048 / 128, 2048 / 64), 256, 0, stream>>>(attno, WoT, d_out, 2048, 2048, hs);
}